// Round 5
// baseline (376.821 us; speedup 1.0000x reference)
//
#include <hip/hip_runtime.h>
#include <stdint.h>

// MultiHeadAttention: B=2, S=2048, D=2048, H=16, Dh=128, fp32 in/out.
// R10: mm_core de-serialized: removed the forced lgkmcnt(0) before each MFMA
//      cluster (plain-C++ ds_reads -> compiler emits per-MFMA lgkmcnt(N),
//      letting LDS reads overlap MFMA) and collapsed 4 barriers/K-tile to 1
//      (ledger: barrier arrival => all waves' MFMAs issued => their ds_reads
//      of buf t%3 retired => safe to restage it at t+1; gload_lds visibility
//      via per-wave vmcnt(6) before the barrier). gemm_out C-store now goes
//      through an LDS fp32 tile (pad 132) -> coalesced float4 stores.
//      conv_all grid-strided (6144 blocks x 4 float4). attn unchanged (R7).

#define SEQ 2048
#define HD 128
#define DMODEL 2048

typedef __bf16 bf16x8 __attribute__((ext_vector_type(8)));
typedef float f32x4 __attribute__((ext_vector_type(4)));
typedef unsigned short u16;
typedef unsigned int u32;

typedef bf16x8 __attribute__((may_alias)) bf16x8_a;
typedef uint2 __attribute__((may_alias)) uint2_a;
typedef uint4 __attribute__((may_alias)) uint4_a;
typedef float4 __attribute__((may_alias)) float4_a;

__device__ __forceinline__ u16 f2bf(float f) {
  unsigned int u = __float_as_uint(f);
  u += 0x7fff + ((u >> 16) & 1);   // RNE; inputs are finite normals
  return (u16)(u >> 16);
}

typedef __attribute__((address_space(1))) void* gas_t;
typedef __attribute__((address_space(3))) void* las_t;
// async global->LDS, 16B/lane. LDS dest must be uniform base + lane*16.
__device__ __forceinline__ void load_lds16(const void* g, void* l) {
  __builtin_amdgcn_global_load_lds((gas_t)(uintptr_t)g,
                                   (las_t)(uint32_t)(uintptr_t)l, 16, 0, 0);
}

// ---------------- fp32 -> bf16 convert (all 5 tensors, one launch) ---------
// 6144 blocks x 256 threads x 4 float4 each = 6291456 float4.
__global__ void conv_all(const float* __restrict__ x,
                         const float* __restrict__ wq,
                         const float* __restrict__ wk,
                         const float* __restrict__ wv,
                         const float* __restrict__ wo,
                         u16* __restrict__ xb, u16* __restrict__ wqkv,
                         u16* __restrict__ wob) {
  int base = blockIdx.x * 256 + threadIdx.x;
#pragma unroll
  for (int rep = 0; rep < 4; ++rep) {
    int i = base + rep * 1572864;
    const float* src;
    u16* dst;
    int off;
    if (i < 2097152) { src = x; dst = xb; off = i; }
    else if (i < 3145728) { src = wq; dst = wqkv; off = i - 2097152; }
    else if (i < 4194304) { src = wk; dst = wqkv + 4194304; off = i - 3145728; }
    else if (i < 5242880) { src = wv; dst = wqkv + 8388608; off = i - 4194304; }
    else { src = wo; dst = wob; off = i - 5242880; }
    float4 v = ((const float4*)src)[off];
    ushort4 o;
    o.x = f2bf(v.x); o.y = f2bf(v.y); o.z = f2bf(v.z); o.w = f2bf(v.w);
    ((ushort4*)dst)[off] = o;
  }
}

// ============== 256x128-tile TRIPLE-buffered GEMM core (R10) ===============
// 8 waves 4M x 2N (wave tile 64x64, acc[4][4]); BK=64, K=2048 (32 K-tiles).
// LDS 144 KiB: A[3][256x64] (96 KB) + B[3][128x64] (48 KB).
// Per tile t (CUR = t%3 compile-time via 3-step unroll), ONE barrier:
//   { ds_read A01+B; STGA(t+2); MFMA(half0); ds_read A23; STGB(t+2);
//     MFMA(half1); vmcnt(6); s_barrier; }
// No forced lgkmcnt(0): reads are plain loads, compiler schedules per-MFMA
// waits so LDS and MFMA pipes overlap. Ledger: at the barrier every wave's
// MFMAs are issued => their ds_reads of buf t%3 retired => buf t%3 is dead
// and may be restaged at t+1 (as (t+3)%3). vmcnt(6) retires stage(t+1)
// (issued at t-1, ~2 tiles of latency cover), leaves stage(t+2) in flight.

#define BARR asm volatile("s_barrier" ::: "memory")
#define VMW6 asm volatile("s_waitcnt vmcnt(6)" ::: "memory")
#define VMW8 asm volatile("s_waitcnt vmcnt(8)" ::: "memory")
#define VMW0 asm volatile("s_waitcnt vmcnt(0)" ::: "memory")

#define STGA(D, KOFF) do {                                                  \
    const u16* ga_ = Ag + (KOFF);                                           \
    u16* la_ = S + (D) * 16384;                                             \
    load_lds16(ga_ + off[0], la_ + tid * 8);                                \
    load_lds16(ga_ + off[1], la_ + (tid + 512) * 8);                        \
    load_lds16(ga_ + off[2], la_ + (tid + 1024) * 8);                       \
    load_lds16(ga_ + off[3], la_ + (tid + 1536) * 8);                       \
  } while (0)

#define STGB(D, KOFF) do {                                                  \
    const u16* gb_ = Bg + (KOFF);                                           \
    u16* lb_ = S + 49152 + (D) * 8192;                                      \
    load_lds16(gb_ + off[0], lb_ + tid * 8);                                \
    load_lds16(gb_ + off[1], lb_ + (tid + 512) * 8);                        \
  } while (0)

#define LDA2(D, MH) do {                                                    \
    const u16* ab_ = S + (D) * 16384;                                       \
    _Pragma("unroll") for (int mt_ = 0; mt_ < 2; ++mt_) {                   \
      int rA_ = wm * 64 + ((MH) * 2 + mt_) * 16 + l15;                      \
      int sw_ = rA_ & 7;                                                    \
      af[mt_][0] = *(const bf16x8_a*)(ab_ + (rA_ * 8 + (quad ^ sw_)) * 8);  \
      af[mt_][1] = *(const bf16x8_a*)(ab_ + (rA_ * 8 + ((4 + quad) ^ sw_)) * 8); \
    } } while (0)

#define LDB2(D) do {                                                        \
    const u16* bb_ = S + 49152 + (D) * 8192;                                \
    _Pragma("unroll") for (int nt_ = 0; nt_ < 4; ++nt_) {                   \
      int rB_ = wn * 64 + nt_ * 16 + l15;                                   \
      int sw_ = rB_ & 7;                                                    \
      bfr[nt_][0] = *(const bf16x8_a*)(bb_ + (rB_ * 8 + (quad ^ sw_)) * 8); \
      bfr[nt_][1] = *(const bf16x8_a*)(bb_ + (rB_ * 8 + ((4 + quad) ^ sw_)) * 8); \
    } } while (0)

#define MM2(MH) do {                                                        \
    __builtin_amdgcn_s_setprio(1);                                          \
    _Pragma("unroll") for (int c_ = 0; c_ < 2; ++c_)                        \
      _Pragma("unroll") for (int mt_ = 0; mt_ < 2; ++mt_)                   \
        _Pragma("unroll") for (int nt_ = 0; nt_ < 4; ++nt_) {               \
          if (VM)                                                           \
            acc[(MH) * 2 + mt_][nt_] =                                      \
                __builtin_amdgcn_mfma_f32_16x16x32_bf16(                    \
                    bfr[nt_][c_], af[mt_][c_],                              \
                    acc[(MH) * 2 + mt_][nt_], 0, 0, 0);                     \
          else                                                              \
            acc[(MH) * 2 + mt_][nt_] =                                      \
                __builtin_amdgcn_mfma_f32_16x16x32_bf16(                    \
                    af[mt_][c_], bfr[nt_][c_],                              \
                    acc[(MH) * 2 + mt_][nt_], 0, 0, 0);                     \
        }                                                                   \
    __builtin_amdgcn_s_setprio(0);                                          \
  } while (0)

// one steady-state K-tile, single barrier; CUR/NX2 compile-time
#define STEP3(T, CUR, NX2) do {                                             \
    LDA2(CUR, 0); LDB2(CUR);                                                \
    STGA(NX2, ((T) + 2) * 64);                                              \
    MM2(0);                                                                 \
    LDA2(CUR, 1);                                                           \
    STGB(NX2, ((T) + 2) * 64);                                              \
    MM2(1);                                                                 \
    VMW6; BARR;                                                             \
  } while (0)

template <bool VM>
__device__ __forceinline__ void mm_core(const u16* __restrict__ Ag,
                                        const u16* __restrict__ Bg,
                                        u16* __restrict__ S, int tid,
                                        f32x4 acc[4][4]) {
  const int lane = tid & 63;
  const int wave = tid >> 6;
  const int quad = lane >> 4;
  const int l15 = lane & 15;
  const int wm = wave >> 1;
  const int wn = wave & 1;

  // staging offsets: atom idx = tid + j*512; row = idx>>3 (stride K=2048);
  // source k8 pre-swizzled by ^(row&7); LDS dest linear (both-sides rule).
  u32 off[4];
#pragma unroll
  for (int j = 0; j < 4; ++j) {
    int idx = tid + j * 512;
    int r = idx >> 3;
    off[j] = (u32)r * 2048u + (u32)(((idx & 7) ^ (r & 7)) * 8);
  }

  bf16x8 af[2][2], bfr[4][2];

  // prologue: tiles 0 and 1 (A+B each); retire tile0, leave tile1 in flight
  STGA(0, 0);
  STGB(0, 0);
  STGA(1, 64);
  STGB(1, 64);
  VMW6;             // tile0's 6 loads retired; tile1's 6 in flight
  BARR;

  // t = 0..29 in groups of 3 (tt = 0,3,...,27 so tt % 3 == 0 always)
#pragma unroll 1
  for (int tt = 0; tt < 30; tt += 3) {
    STEP3(tt,     0, 2);
    STEP3(tt + 1, 1, 0);
    STEP3(tt + 2, 2, 1);
  }

  // t = 30 (CUR=0): no staging; drain stage(31) for t=31
  LDA2(0, 0); LDB2(0);
  MM2(0);
  LDA2(0, 1);
  MM2(1);
  VMW0; BARR;
  // t = 31 (CUR=1)
  LDA2(1, 0); LDB2(1);
  MM2(0);
  LDA2(1, 1);
  MM2(1);
  BARR;             // all reads done before epilogue reuses S
}

// grid (48, 16), 512 threads. bx<16: Q RoPE; 16-31: K RoPE; 32-47: V^T.
__global__ __launch_bounds__(512, 2)
void gemm_qkv(const u16* __restrict__ A, const u16* __restrict__ Bm,
              u16* __restrict__ qkv, u16* __restrict__ vt) {
  __shared__ __align__(16) u16 S[73728];  // 144 KiB: A[3][16384]+B[3][8192]

  const int tid = threadIdx.x;
  // XCD-aware bijective swizzle, col-major logical order: each XCD owns 6
  // consecutive B-panels (weights resident in its L2); A panels hit L3.
  int hwid = blockIdx.y * 48 + blockIdx.x;
  int logical = (hwid & 7) * 96 + (hwid >> 3);
  const int bx = logical >> 4;       // 0..47 (N tile, 128 cols = 1 head)
  const int by = logical & 15;       // 0..15 (M tile, 256 rows)
  const int row0 = by * 256;
  const int col0 = bx * 128;
  const bool vmode = bx >= 32;

  const u16* Ag = A + (size_t)row0 * 2048;
  const u16* Bg = Bm + (size_t)col0 * 2048;

  f32x4 acc[4][4] = {};
  if (vmode) mm_core<true>(Ag, Bg, S, tid, acc);
  else       mm_core<false>(Ag, Bg, S, tid, acc);

  const int lane = tid & 63;
  const int wave = tid >> 6;
  const int quad = lane >> 4;
  const int l15 = lane & 15;
  const int wm = wave >> 1;
  const int wn = wave & 1;

  const int which = bx >> 4;              // 0=q 1=k 2=v
  const int h = bx & 15;
  const int brow = row0 >> 11;
  const int sbase = row0 & 2047;
  const float qs = (which == 0) ? 0.12751744f : 1.0f;  // log2e/sqrt(128)

  // acc -> bf16 tile in S (reuses A region), atom-XOR swizzled
#pragma unroll
  for (int mt = 0; mt < 4; ++mt)
#pragma unroll
    for (int nt = 0; nt < 4; ++nt)
#pragma unroll
      for (int r = 0; r < 4; ++r) {
        int el;
        if (vmode) {  // C^T tile [d=128][s=256], 32 atoms/row
          int dd = wn * 64 + nt * 16 + quad * 4 + r;
          int ss = wm * 64 + mt * 16 + l15;
          el = dd * 256 + (((ss >> 3) ^ (dd & 31)) * 8) + (ss & 7);
        } else {      // tile [s=256][d=128], 16 atoms/row
          int ss = wm * 64 + mt * 16 + quad * 4 + r;
          int dd = wn * 64 + nt * 16 + l15;
          el = ss * 128 + (((dd >> 3) ^ (ss & 15)) * 8) + (dd & 7);
        }
        S[el] = f2bf(acc[mt][nt][r] * qs);
      }
  __syncthreads();

  if (!vmode) {
    const int a = lane & 7;     // d-atom 0..7 (pairs with a+8)
    const int sg = lane >> 3;   // row-in-group
    const float c1 = 0.2076205059304601f;   // log2(10000)/64
    const float c2 = 2.6514961294723187f;   // log2(2*pi)
#pragma unroll
    for (int pass = 0; pass < 4; ++pass) {
      int s_l = pass * 64 + wave * 8 + sg;
      int s2048 = sbase + s_l;
      int sw = s_l & 15;
      bf16x8 x1 = *(const bf16x8_a*)&S[s_l * 128 + ((a ^ sw) * 8)];
      bf16x8 x2 = *(const bf16x8_a*)&S[s_l * 128 + (((a + 8) ^ sw) * 8)];
      u16 o1[8], o2[8];
#pragma unroll
      for (int e = 0; e < 8; ++e) {
        float j = (float)(a * 8 + e);
        float rev = (float)s2048 * __builtin_amdgcn_exp2f(-c1 * j - c2);
        rev = __builtin_amdgcn_fractf(rev);
        float sn = __builtin_amdgcn_sinf(rev);
        float cs = __builtin_amdgcn_cosf(rev);
        float v1 = (float)x1[e], v2 = (float)x2[e];
        o1[e] = f2bf(v1 * cs - v2 * sn);
        o2[e] = f2bf(v2 * cs + v1 * sn);
      }
      size_t base =
          ((((size_t)which * 2 + brow) * 16 + h) * SEQ + s2048) * HD + a * 8;
      *(uint4_a*)&qkv[base] = *(uint4*)o1;
      *(uint4_a*)&qkv[base + 64] = *(uint4*)o2;
    }
  } else {  // V: transposed copy-out, vt[b,h,d,s]
    const int d_part = tid >> 4;        // 0..31
    const int a0 = tid & 15;            // atom 0..15 (+16 for second)
#pragma unroll
    for (int pass = 0; pass < 4; ++pass) {
      int d_l = pass * 32 + d_part;     // 0..127
      int dw = d_l & 31;
      size_t rb = (((size_t)brow * 16 + h) * HD + d_l) * SEQ + sbase;
#pragma unroll
      for (int g = 0; g < 2; ++g) {
        int a2 = a0 + g * 16;
        bf16x8 y = *(const bf16x8_a*)&S[d_l * 256 + ((a2 ^ dw) * 8)];
        *(uint4_a*)&vt[rb + a2 * 8] = *(uint4_a*)&y;
      }
    }
  }
}

// ---------------- output GEMM: same core; LDS-staged float4 C-store --------
// grid (16, 16) = 256 blocks = exactly 1 CU-round.
__global__ __launch_bounds__(512, 2)
void gemm_out(const u16* __restrict__ A, const u16* __restrict__ Bm,
              float* __restrict__ C, const float* __restrict__ bias) {
  __shared__ __align__(16) u16 S[73728];  // 144 KiB

  const int tid = threadIdx.x;
  int hwid = blockIdx.y * 16 + blockIdx.x;
  int logical = (hwid & 7) * 32 + (hwid >> 3);
  const int bx = logical >> 4;       // 0..15 (N tile)
  const int by = logical & 15;       // 0..15 (M tile)
  const int row0 = by * 256;
  const int col0 = bx * 128;

  const u16* Ag = A + (size_t)row0 * 2048;
  const u16* Bg = Bm + (size_t)col0 * 2048;

  f32x4 acc[4][4] = {};
  mm_core<false>(Ag, Bg, S, tid, acc);

  const int lane = tid & 63;
  const int wave = tid >> 6;
  const int quad = lane >> 4;
  const int l15 = lane & 15;
  const int wm = wave >> 1;
  const int wn = wave & 1;

  // bias into acc
#pragma unroll
  for (int nt = 0; nt < 4; ++nt) {
    float bv = bias[col0 + wn * 64 + nt * 16 + l15];
#pragma unroll
    for (int mt = 0; mt < 4; ++mt)
#pragma unroll
      for (int r = 0; r < 4; ++r) acc[mt][nt][r] += bv;
  }

  // two 128-row halves through an LDS fp32 tile [128][132] -> float4 stores
  float* Sf = (float*)S;  // 132*128*4 = 67584 B <= 147456 B
  const int lr = tid >> 2;
  const int c16 = (tid & 3) << 5;
#pragma unroll
  for (int hh = 0; hh < 2; ++hh) {
    if ((wm >> 1) == hh) {
      int lrow0 = (wm & 1) * 64;
#pragma unroll
      for (int mt = 0; mt < 4; ++mt)
#pragma unroll
        for (int nt = 0; nt < 4; ++nt)
#pragma unroll
          for (int r = 0; r < 4; ++r) {
            int lrow = lrow0 + mt * 16 + quad * 4 + r;
            int col = wn * 64 + nt * 16 + l15;
            Sf[lrow * 132 + col] = acc[mt][nt][r];
          }
    }
    __syncthreads();
#pragma unroll
    for (int k = 0; k < 8; ++k) {
      float4 v = *(const float4_a*)&Sf[lr * 132 + c16 + k * 4];
      *(float4_a*)&C[(size_t)(row0 + hh * 128 + lr) * DMODEL + col0 + c16 +
                     k * 4] = v;
    }
    __syncthreads();
  }
}

// ---------------- Flash attention (R7: KV dbuf + counted vmcnt) ------------
// grid (S/128, B*H), 4 waves; wave owns 32 Q rows (2 m-tiles).
// Per tile t: compute on buf[t&1]; BARR; stage(t+2)->buf[t&1]; vmcnt(8)
// (stage(t+1) retired, stage(t+2) in flight); BARR. Staging latency hides
// under one full compute phase. setprio(1) around both MFMA clusters.
__global__ __launch_bounds__(256, 2)
void attn_kernel(const u16* __restrict__ qkv, const u16* __restrict__ vt,
                 u16* __restrict__ attn_out) {
  __shared__ __align__(16) u16 Kl[2][64 * 128];   // [kv][hd] swizzled atoms
  __shared__ __align__(16) u16 Vl[2][128 * 64];   // [d][kv] swizzled atoms
  __shared__ __align__(16) u16 Pl[4][32 * 64];    // per-wave [q][kv] swizzled

  const int tid = threadIdx.x;
  const int lane = tid & 63;
  const int wave = tid >> 6;
  const int quad = lane >> 4;
  const int l15 = lane & 15;
  const int q0 = blockIdx.x * 128;
  const int bh = blockIdx.y;
  const size_t SD = (size_t)SEQ * HD;

  const u16* Q = qkv + (size_t)bh * SD;          // which=0 (pre-scaled)
  const u16* Kg = qkv + (size_t)(32 + bh) * SD;  // which=1
  const u16* Vg = vt + (size_t)bh * SD;          // [d][s]

  // ones A-fragment in registers: row m=0 (lanes l15==0) = 1.0, else 0.
  bf16x8 onesf;
#pragma unroll
  for (int e = 0; e < 8; ++e)
    onesf[e] = (l15 == 0) ? (__bf16)1.0f : (__bf16)0.0f;

  // Q fragments first: oldest in the vmcnt FIFO, retired before first use.
  bf16x8 qf[2][4];  // Q[q=mt*16+l15][hd=c*32+quad*8+j]
#pragma unroll
  for (int mt = 0; mt < 2; ++mt) {
    int qrow = q0 + wave * 32 + mt * 16 + l15;
#pragma unroll
    for (int c = 0; c < 4; ++c)
      qf[mt][c] = *(const bf16x8*)(Q + (size_t)qrow * HD + c * 32 + quad * 8);
  }

  f32x4 of[9][2] = {};   // of[0..7]: O^T[d][q]; of[8] row0: l (ones frag)
  u16* pw = &Pl[wave][0];

  // stage one 64-wide KV tile into buffer `buf` (8 loads/thread)
  auto stage = [&](int tile, int buf) {
    int kv0 = tile * 64;
#pragma unroll
    for (int j = 0; j < 4; ++j) {
      int idx = (wave * 4 + j) * 64 + lane;
      {  // K: 64 rows x 16 atoms, swizzle ^(row&15)
        int r = idx >> 4, cs = idx & 15;
        int cc = cs ^ (r & 15);
        load_lds16(Kg + (size_t)(kv0 + r) * HD + cc * 8, &Kl[buf][idx * 8]);
      }
      {  // VT: 128 rows x 8 atoms, swizzle ^(row&7)
        int r = idx >> 3, cs = idx & 7;
        int cc = cs ^ (r & 7);
        load_lds16(Vg + (size_t)r * SEQ + kv0 + cc * 8, &Vl[buf][idx * 8]);
      }
    }
  };

  // prologue: tiles 0 and 1; vmcnt(8) = stage(0) retired (stage(1) in flight)
  stage(0, 0);
  stage(1, 1);
  VMW8;
  BARR;

#pragma unroll 2
  for (int t = 0; t < 32; ++t) {
    const u16* Kb = Kl[t & 1];
    const u16* Vb = Vl[t & 1];

    // S^T tiles: sc[nt][mt], rows kv=nt*16+quad*4+r, cols q=mt*16+l15
    f32x4 sc[4][2] = {};
    __builtin_amdgcn_s_setprio(1);
#pragma unroll
    for (int c = 0; c < 4; ++c) {
      bf16x8 kf[4];
#pragma unroll
      for (int nt = 0; nt < 4; ++nt)
        kf[nt] = *(const bf16x8*)&Kb[((nt * 16 + l15) * 16 +
                                      ((c * 4 + quad) ^ l15)) * 8];
#pragma unroll
      for (int nt = 0; nt < 4; ++nt)
#pragma unroll
        for (int mt = 0; mt < 2; ++mt)
          sc[nt][mt] = __builtin_amdgcn_mfma_f32_16x16x32_bf16(
              kf[nt], qf[mt][c], sc[nt][mt], 0, 0, 0);
    }
    __builtin_amdgcn_s_setprio(0);

    // P = exp2(sc); truncate-pack via v_perm; b64 writes (wave-private Pl)
#pragma unroll
    for (int nt = 0; nt < 4; ++nt) {
#pragma unroll
      for (int mt = 0; mt < 2; ++mt) {
        float p0 = __builtin_amdgcn_exp2f(sc[nt][mt][0]);
        float p1 = __builtin_amdgcn_exp2f(sc[nt][mt][1]);
        float p2 = __builtin_amdgcn_exp2f(sc[nt][mt][2]);
        float p3 = __builtin_amdgcn_exp2f(sc[nt][mt][3]);
        u32 lo = __builtin_amdgcn_perm(__float_as_uint(p1),
                                       __float_as_uint(p0), 0x07060302u);
        u32 hi = __builtin_amdgcn_perm(__float_as_uint(p3),
                                       __float_as_uint(p2), 0x07060302u);
        int row = mt * 16 + l15;
        int a = nt * 2 + (quad >> 1);
        int idx16 = (row * 8 + (a ^ (l15 & 7))) * 8 + (quad & 1) * 4;
        uint2 pk; pk.x = lo; pk.y = hi;
        *(uint2_a*)&pw[idx16] = pk;
      }
    }

    // O^T += V^T.P ; dt=8 uses the register ones-frag -> row sums (l)
    __builtin_amdgcn_s_setprio(1);
#pragma unroll
    for (int c = 0; c < 2; ++c) {
      bf16x8 pf[2];
#pragma unroll
      for (int mt = 0; mt < 2; ++mt)
        pf[mt] = *(const bf16x8_a*)&pw[((mt * 16 + l15) * 8 +
                                        ((c * 4 + quad) ^ (l15 & 7))) * 8];
#pragma unroll
      for (int dt = 0; dt < 9; ++dt) {
        bf16x8 vf = (dt < 8)
                        ? *(const bf16x8*)&Vb[((dt * 16 + l15) * 8 +
                                               ((c * 4 + quad) ^ (l15 & 7))) * 8]
                        : onesf;
#pragma unroll
        for (int mt = 0; mt < 2; ++mt)
          of[dt][mt] = __builtin_amdgcn_mfma_f32_16x16x32_bf16(
              vf, pf[mt], of[dt][mt], 0, 0, 0);
      }
    }
    __builtin_amdgcn_s_setprio(0);

    // all waves done reading buf[t&1]; restage it for tile t+2
    BARR;
    if (t < 30) {
      stage(t + 2, t & 1);
      VMW8;              // stage(t+1) retired; stage(t+2) stays in flight
    } else {
      VMW0;              // tail: drain (covers stage(31) at t=30)
    }
    BARR;
  }

  // l lives at of[8][mt][0] on quad-0 lanes (C row 0); broadcast by shfl.
  const int b = bh >> 4, h = bh & 15;
#pragma unroll
  for (int mt = 0; mt < 2; ++mt) {
    float lsum = __shfl(of[8][mt][0], l15, 64);
    float inv = 1.f / lsum;
    int s = q0 + wave * 32 + mt * 16 + l15;
    size_t rowb = ((size_t)b * SEQ + s) * DMODEL + h * HD;
#pragma unroll
    for (int dt = 0; dt < 8; ++dt) {
      ushort4 ov;
      ov.x = f2bf(of[dt][mt][0] * inv);
      ov.y = f2bf(of[dt][mt][1] * inv);
      ov.z = f2bf(of[dt][mt][2] * inv);
      ov.w = f2bf(of[dt][mt][3] * inv);
      *(ushort4*)&attn_out[rowb + dt * 16 + quad * 4] = ov;
    }
  }
}

extern "C" void kernel_launch(void* const* d_in, const int* in_sizes, int n_in,
                              void* d_out, int out_size, void* d_ws,
                              size_t ws_size, hipStream_t stream) {
  const float* x = (const float*)d_in[0];
  const float* Wq = (const float*)d_in[1];
  const float* Wk = (const float*)d_in[2];
  const float* Wv = (const float*)d_in[3];
  const float* Wo = (const float*)d_in[4];
  const float* bo = (const float*)d_in[5];
  float* out = (float*)d_out;

  char* ws = (char*)d_ws;
  u16* xb = (u16*)(ws);                              // 16 MiB
  u16* wqkv = (u16*)(ws + (size_t)(16 << 20));       // 24 MiB
  u16* wob = (u16*)(ws + (size_t)(40 << 20));        // 8 MiB
  u16* qkv = (u16*)(ws + (size_t)(48 << 20));        // 48 MiB: Q | K | vt
  u16* vt = qkv + (size_t)2 * 8388608;               // vt in the V slot
  u16* attn = xb;                                    // reuse after GEMMs

  // fp32 -> bf16 (one fused launch, grid-strided)
  conv_all<<<6144, 256, 0, stream>>>(x, Wq, Wk, Wv, Wo, xb, wqkv, wob);

  // Q,K (fused RoPE) + V^T: 256x128 tiles, 768 blocks = 3 exact CU-rounds
  gemm_qkv<<<dim3(48, 16), 512, 0, stream>>>(xb, wqkv, qkv, vt);
  // flash attention
  attn_kernel<<<dim3(16, 32), 256, 0, stream>>>(qkv, vt, attn);
  // out = attn @ wob^T + bo: 256x128 tiles, 256 blocks = 1 exact CU-round
  gemm_out<<<dim3(16, 16), 512, 0, stream>>>(attn, wob, out, bo);
}

// Round 6
// 367.233 us; speedup vs baseline: 1.0261x; 1.0261x over previous
//
#include <hip/hip_runtime.h>
#include <stdint.h>

// MultiHeadAttention: B=2, S=2048, D=2048, H=16, Dh=128, fp32 in/out.
// R11: attn_kernel -> 8 waves x 16 q-rows (512 thr), 4 waves/SIMD for
//      phase overlap (was 2); LDS exactly 80 KiB -> still 2 blocks/CU;
//      vmcnt(4) ledger. conv_all and gemm_out epilogue reverted to the
//      R9-measured forms (R10's unverified variants suspected for the
//      +20us e2e regression). mm_core kept at R10 (verified 116->108,
//      MfmaUtil 37->41).

#define SEQ 2048
#define HD 128
#define DMODEL 2048

typedef __bf16 bf16x8 __attribute__((ext_vector_type(8)));
typedef float f32x4 __attribute__((ext_vector_type(4)));
typedef unsigned short u16;
typedef unsigned int u32;

typedef bf16x8 __attribute__((may_alias)) bf16x8_a;
typedef uint2 __attribute__((may_alias)) uint2_a;
typedef uint4 __attribute__((may_alias)) uint4_a;

__device__ __forceinline__ u16 f2bf(float f) {
  unsigned int u = __float_as_uint(f);
  u += 0x7fff + ((u >> 16) & 1);   // RNE; inputs are finite normals
  return (u16)(u >> 16);
}

typedef __attribute__((address_space(1))) void* gas_t;
typedef __attribute__((address_space(3))) void* las_t;
// async global->LDS, 16B/lane. LDS dest must be uniform base + lane*16.
__device__ __forceinline__ void load_lds16(const void* g, void* l) {
  __builtin_amdgcn_global_load_lds((gas_t)(uintptr_t)g,
                                   (las_t)(uint32_t)(uintptr_t)l, 16, 0, 0);
}

// ---------------- fp32 -> bf16 convert (all 5 tensors, one launch) ---------
__global__ void conv_all(const float* __restrict__ x,
                         const float* __restrict__ wq,
                         const float* __restrict__ wk,
                         const float* __restrict__ wv,
                         const float* __restrict__ wo,
                         u16* __restrict__ xb, u16* __restrict__ wqkv,
                         u16* __restrict__ wob) {
  int i = blockIdx.x * 256 + threadIdx.x;  // float4 index
  const float* src;
  u16* dst;
  int off;
  if (i < 2097152) { src = x; dst = xb; off = i; }
  else if (i < 3145728) { src = wq; dst = wqkv; off = i - 2097152; }
  else if (i < 4194304) { src = wk; dst = wqkv + 4194304; off = i - 3145728; }
  else if (i < 5242880) { src = wv; dst = wqkv + 8388608; off = i - 4194304; }
  else { src = wo; dst = wob; off = i - 5242880; }
  float4 v = ((const float4*)src)[off];
  ushort4 o;
  o.x = f2bf(v.x); o.y = f2bf(v.y); o.z = f2bf(v.z); o.w = f2bf(v.w);
  ((ushort4*)dst)[off] = o;
}

// ============== 256x128-tile TRIPLE-buffered GEMM core (R10) ===============
// 8 waves 4M x 2N (wave tile 64x64, acc[4][4]); BK=64, K=2048 (32 K-tiles).
// LDS 144 KiB: A[3][256x64] (96 KB) + B[3][128x64] (48 KB).
// Per tile t (CUR = t%3 compile-time via 3-step unroll), ONE barrier:
//   { ds_read A01+B; STGA(t+2); MFMA(half0); ds_read A23; STGB(t+2);
//     MFMA(half1); vmcnt(6); s_barrier; }
// No forced lgkmcnt(0): reads are plain loads, compiler schedules per-MFMA
// waits so LDS and MFMA pipes overlap. Ledger: at the barrier every wave's
// MFMAs are issued => their ds_reads of buf t%3 retired => buf t%3 is dead
// and may be restaged at t+1 (as (t+3)%3). vmcnt(6) retires stage(t+1)
// (issued at t-1, ~2 tiles of latency cover), leaves stage(t+2) in flight.

#define BARR asm volatile("s_barrier" ::: "memory")
#define VMW6 asm volatile("s_waitcnt vmcnt(6)" ::: "memory")
#define VMW4 asm volatile("s_waitcnt vmcnt(4)" ::: "memory")
#define VMW0 asm volatile("s_waitcnt vmcnt(0)" ::: "memory")

#define STGA(D, KOFF) do {                                                  \
    const u16* ga_ = Ag + (KOFF);                                           \
    u16* la_ = S + (D) * 16384;                                             \
    load_lds16(ga_ + off[0], la_ + tid * 8);                                \
    load_lds16(ga_ + off[1], la_ + (tid + 512) * 8);                        \
    load_lds16(ga_ + off[2], la_ + (tid + 1024) * 8);                       \
    load_lds16(ga_ + off[3], la_ + (tid + 1536) * 8);                       \
  } while (0)

#define STGB(D, KOFF) do {                                                  \
    const u16* gb_ = Bg + (KOFF);                                           \
    u16* lb_ = S + 49152 + (D) * 8192;                                      \
    load_lds16(gb_ + off[0], lb_ + tid * 8);                                \
    load_lds16(gb_ + off[1], lb_ + (tid + 512) * 8);                        \
  } while (0)

#define LDA2(D, MH) do {                                                    \
    const u16* ab_ = S + (D) * 16384;                                       \
    _Pragma("unroll") for (int mt_ = 0; mt_ < 2; ++mt_) {                   \
      int rA_ = wm * 64 + ((MH) * 2 + mt_) * 16 + l15;                      \
      int sw_ = rA_ & 7;                                                    \
      af[mt_][0] = *(const bf16x8_a*)(ab_ + (rA_ * 8 + (quad ^ sw_)) * 8);  \
      af[mt_][1] = *(const bf16x8_a*)(ab_ + (rA_ * 8 + ((4 + quad) ^ sw_)) * 8); \
    } } while (0)

#define LDB2(D) do {                                                        \
    const u16* bb_ = S + 49152 + (D) * 8192;                                \
    _Pragma("unroll") for (int nt_ = 0; nt_ < 4; ++nt_) {                   \
      int rB_ = wn * 64 + nt_ * 16 + l15;                                   \
      int sw_ = rB_ & 7;                                                    \
      bfr[nt_][0] = *(const bf16x8_a*)(bb_ + (rB_ * 8 + (quad ^ sw_)) * 8); \
      bfr[nt_][1] = *(const bf16x8_a*)(bb_ + (rB_ * 8 + ((4 + quad) ^ sw_)) * 8); \
    } } while (0)

#define MM2(MH) do {                                                        \
    __builtin_amdgcn_s_setprio(1);                                          \
    _Pragma("unroll") for (int c_ = 0; c_ < 2; ++c_)                        \
      _Pragma("unroll") for (int mt_ = 0; mt_ < 2; ++mt_)                   \
        _Pragma("unroll") for (int nt_ = 0; nt_ < 4; ++nt_) {               \
          if (VM)                                                           \
            acc[(MH) * 2 + mt_][nt_] =                                      \
                __builtin_amdgcn_mfma_f32_16x16x32_bf16(                    \
                    bfr[nt_][c_], af[mt_][c_],                              \
                    acc[(MH) * 2 + mt_][nt_], 0, 0, 0);                     \
          else                                                              \
            acc[(MH) * 2 + mt_][nt_] =                                      \
                __builtin_amdgcn_mfma_f32_16x16x32_bf16(                    \
                    af[mt_][c_], bfr[nt_][c_],                              \
                    acc[(MH) * 2 + mt_][nt_], 0, 0, 0);                     \
        }                                                                   \
    __builtin_amdgcn_s_setprio(0);                                          \
  } while (0)

// one steady-state K-tile, single barrier; CUR/NX2 compile-time
#define STEP3(T, CUR, NX2) do {                                             \
    LDA2(CUR, 0); LDB2(CUR);                                                \
    STGA(NX2, ((T) + 2) * 64);                                              \
    MM2(0);                                                                 \
    LDA2(CUR, 1);                                                           \
    STGB(NX2, ((T) + 2) * 64);                                              \
    MM2(1);                                                                 \
    VMW6; BARR;                                                             \
  } while (0)

template <bool VM>
__device__ __forceinline__ void mm_core(const u16* __restrict__ Ag,
                                        const u16* __restrict__ Bg,
                                        u16* __restrict__ S, int tid,
                                        f32x4 acc[4][4]) {
  const int lane = tid & 63;
  const int wave = tid >> 6;
  const int quad = lane >> 4;
  const int l15 = lane & 15;
  const int wm = wave >> 1;
  const int wn = wave & 1;

  // staging offsets: atom idx = tid + j*512; row = idx>>3 (stride K=2048);
  // source k8 pre-swizzled by ^(row&7); LDS dest linear (both-sides rule).
  u32 off[4];
#pragma unroll
  for (int j = 0; j < 4; ++j) {
    int idx = tid + j * 512;
    int r = idx >> 3;
    off[j] = (u32)r * 2048u + (u32)(((idx & 7) ^ (r & 7)) * 8);
  }

  bf16x8 af[2][2], bfr[4][2];

  // prologue: tiles 0 and 1 (A+B each); retire tile0, leave tile1 in flight
  STGA(0, 0);
  STGB(0, 0);
  STGA(1, 64);
  STGB(1, 64);
  VMW6;             // tile0's 6 loads retired; tile1's 6 in flight
  BARR;

  // t = 0..29 in groups of 3 (tt = 0,3,...,27 so tt % 3 == 0 always)
#pragma unroll 1
  for (int tt = 0; tt < 30; tt += 3) {
    STEP3(tt,     0, 2);
    STEP3(tt + 1, 1, 0);
    STEP3(tt + 2, 2, 1);
  }

  // t = 30 (CUR=0): no staging; drain stage(31) for t=31
  LDA2(0, 0); LDB2(0);
  MM2(0);
  LDA2(0, 1);
  MM2(1);
  VMW0; BARR;
  // t = 31 (CUR=1)
  LDA2(1, 0); LDB2(1);
  MM2(0);
  LDA2(1, 1);
  MM2(1);
  BARR;             // all reads done before epilogue reuses S
}

// grid (48, 16), 512 threads. bx<16: Q RoPE; 16-31: K RoPE; 32-47: V^T.
__global__ __launch_bounds__(512, 2)
void gemm_qkv(const u16* __restrict__ A, const u16* __restrict__ Bm,
              u16* __restrict__ qkv, u16* __restrict__ vt) {
  __shared__ __align__(16) u16 S[73728];  // 144 KiB: A[3][16384]+B[3][8192]

  const int tid = threadIdx.x;
  // XCD-aware bijective swizzle, col-major logical order: each XCD owns 6
  // consecutive B-panels (weights resident in its L2); A panels hit L3.
  int hwid = blockIdx.y * 48 + blockIdx.x;
  int logical = (hwid & 7) * 96 + (hwid >> 3);
  const int bx = logical >> 4;       // 0..47 (N tile, 128 cols = 1 head)
  const int by = logical & 15;       // 0..15 (M tile, 256 rows)
  const int row0 = by * 256;
  const int col0 = bx * 128;
  const bool vmode = bx >= 32;

  const u16* Ag = A + (size_t)row0 * 2048;
  const u16* Bg = Bm + (size_t)col0 * 2048;

  f32x4 acc[4][4] = {};
  if (vmode) mm_core<true>(Ag, Bg, S, tid, acc);
  else       mm_core<false>(Ag, Bg, S, tid, acc);

  const int lane = tid & 63;
  const int wave = tid >> 6;
  const int quad = lane >> 4;
  const int l15 = lane & 15;
  const int wm = wave >> 1;
  const int wn = wave & 1;

  const int which = bx >> 4;              // 0=q 1=k 2=v
  const int h = bx & 15;
  const int brow = row0 >> 11;
  const int sbase = row0 & 2047;
  const float qs = (which == 0) ? 0.12751744f : 1.0f;  // log2e/sqrt(128)

  // acc -> bf16 tile in S (reuses A region), atom-XOR swizzled
#pragma unroll
  for (int mt = 0; mt < 4; ++mt)
#pragma unroll
    for (int nt = 0; nt < 4; ++nt)
#pragma unroll
      for (int r = 0; r < 4; ++r) {
        int el;
        if (vmode) {  // C^T tile [d=128][s=256], 32 atoms/row
          int dd = wn * 64 + nt * 16 + quad * 4 + r;
          int ss = wm * 64 + mt * 16 + l15;
          el = dd * 256 + (((ss >> 3) ^ (dd & 31)) * 8) + (ss & 7);
        } else {      // tile [s=256][d=128], 16 atoms/row
          int ss = wm * 64 + mt * 16 + quad * 4 + r;
          int dd = wn * 64 + nt * 16 + l15;
          el = ss * 128 + (((dd >> 3) ^ (ss & 15)) * 8) + (dd & 7);
        }
        S[el] = f2bf(acc[mt][nt][r] * qs);
      }
  __syncthreads();

  if (!vmode) {
    const int a = lane & 7;     // d-atom 0..7 (pairs with a+8)
    const int sg = lane >> 3;   // row-in-group
    const float c1 = 0.2076205059304601f;   // log2(10000)/64
    const float c2 = 2.6514961294723187f;   // log2(2*pi)
#pragma unroll
    for (int pass = 0; pass < 4; ++pass) {
      int s_l = pass * 64 + wave * 8 + sg;
      int s2048 = sbase + s_l;
      int sw = s_l & 15;
      bf16x8 x1 = *(const bf16x8_a*)&S[s_l * 128 + ((a ^ sw) * 8)];
      bf16x8 x2 = *(const bf16x8_a*)&S[s_l * 128 + (((a + 8) ^ sw) * 8)];
      u16 o1[8], o2[8];
#pragma unroll
      for (int e = 0; e < 8; ++e) {
        float j = (float)(a * 8 + e);
        float rev = (float)s2048 * __builtin_amdgcn_exp2f(-c1 * j - c2);
        rev = __builtin_amdgcn_fractf(rev);
        float sn = __builtin_amdgcn_sinf(rev);
        float cs = __builtin_amdgcn_cosf(rev);
        float v1 = (float)x1[e], v2 = (float)x2[e];
        o1[e] = f2bf(v1 * cs - v2 * sn);
        o2[e] = f2bf(v2 * cs + v1 * sn);
      }
      size_t base =
          ((((size_t)which * 2 + brow) * 16 + h) * SEQ + s2048) * HD + a * 8;
      *(uint4_a*)&qkv[base] = *(uint4*)o1;
      *(uint4_a*)&qkv[base + 64] = *(uint4*)o2;
    }
  } else {  // V: transposed copy-out, vt[b,h,d,s]
    const int d_part = tid >> 4;        // 0..31
    const int a0 = tid & 15;            // atom 0..15 (+16 for second)
#pragma unroll
    for (int pass = 0; pass < 4; ++pass) {
      int d_l = pass * 32 + d_part;     // 0..127
      int dw = d_l & 31;
      size_t rb = (((size_t)brow * 16 + h) * HD + d_l) * SEQ + sbase;
#pragma unroll
      for (int g = 0; g < 2; ++g) {
        int a2 = a0 + g * 16;
        bf16x8 y = *(const bf16x8_a*)&S[d_l * 256 + ((a2 ^ dw) * 8)];
        *(uint4_a*)&vt[rb + a2 * 8] = *(uint4_a*)&y;
      }
    }
  }
}

// ---------------- output GEMM: same core, fp32 + bias epilogue (R9) --------
// grid (16, 16) = 256 blocks = exactly 1 CU-round.
__global__ __launch_bounds__(512, 2)
void gemm_out(const u16* __restrict__ A, const u16* __restrict__ Bm,
              float* __restrict__ C, const float* __restrict__ bias) {
  __shared__ __align__(16) u16 S[73728];  // 144 KiB

  const int tid = threadIdx.x;
  int hwid = blockIdx.y * 16 + blockIdx.x;
  int logical = (hwid & 7) * 32 + (hwid >> 3);
  const int bx = logical >> 4;       // 0..15 (N tile)
  const int by = logical & 15;       // 0..15 (M tile)
  const int row0 = by * 256;
  const int col0 = bx * 128;

  const u16* Ag = A + (size_t)row0 * 2048;
  const u16* Bg = Bm + (size_t)col0 * 2048;

  f32x4 acc[4][4] = {};
  mm_core<false>(Ag, Bg, S, tid, acc);

  const int lane = tid & 63;
  const int wave = tid >> 6;
  const int quad = lane >> 4;
  const int l15 = lane & 15;
  const int wm = wave >> 1;
  const int wn = wave & 1;

#pragma unroll
  for (int nt = 0; nt < 4; ++nt) {
    int d = col0 + wn * 64 + nt * 16 + l15;
    float bv = bias[d];
#pragma unroll
    for (int mt = 0; mt < 4; ++mt) {
#pragma unroll
      for (int r = 0; r < 4; ++r) {
        int row = row0 + wm * 64 + mt * 16 + quad * 4 + r;
        C[(size_t)row * DMODEL + d] = acc[mt][nt][r] + bv;
      }
    }
  }
}

// ---------------- Flash attention (R11: 8 waves x 16 q-rows) ---------------
// grid (S/128, B*H), 512 threads; wave owns 16 Q rows (1 m-tile).
// 4 waves/SIMD (2 blocks/CU x 8 waves) so QK^T/softmax/PV phases of
// different waves interleave on the MFMA pipe. KV double-buffer; per tile:
// compute(t) on buf[t&1]; BARR; stage(t+2)->buf[t&1]; vmcnt(4) (retires
// stage(t+1), leaves stage(t+2) in flight); BARR. LDS = 80 KiB exactly.
__global__ __launch_bounds__(512, 4)
void attn_kernel(const u16* __restrict__ qkv, const u16* __restrict__ vt,
                 u16* __restrict__ attn_out) {
  __shared__ __align__(16) u16 Kl[2][64 * 128];   // [kv][hd] swizzled atoms
  __shared__ __align__(16) u16 Vl[2][128 * 64];   // [d][kv] swizzled atoms
  __shared__ __align__(16) u16 Pl[8][16 * 64];    // per-wave [q][kv] swizzled

  const int tid = threadIdx.x;
  const int lane = tid & 63;
  const int wave = tid >> 6;          // 0..7
  const int quad = lane >> 4;
  const int l15 = lane & 15;
  const int q0 = blockIdx.x * 128;
  const int bh = blockIdx.y;
  const size_t SD = (size_t)SEQ * HD;

  const u16* Q = qkv + (size_t)bh * SD;          // which=0 (pre-scaled)
  const u16* Kg = qkv + (size_t)(32 + bh) * SD;  // which=1
  const u16* Vg = vt + (size_t)bh * SD;          // [d][s]

  // ones A-fragment in registers: row m=0 (lanes l15==0) = 1.0, else 0.
  bf16x8 onesf;
#pragma unroll
  for (int e = 0; e < 8; ++e)
    onesf[e] = (l15 == 0) ? (__bf16)1.0f : (__bf16)0.0f;

  // Q fragments first: oldest in the vmcnt FIFO, retired by prologue VMW4.
  bf16x8 qf[4];  // Q[q=wave*16+l15][hd=c*32+quad*8+j]
  {
    int qrow = q0 + wave * 16 + l15;
#pragma unroll
    for (int c = 0; c < 4; ++c)
      qf[c] = *(const bf16x8*)(Q + (size_t)qrow * HD + c * 32 + quad * 8);
  }

  f32x4 of[9] = {};   // of[0..7]: O^T[d][q]; of[8] row0: l (ones frag)
  u16* pw = &Pl[wave][0];

  // stage one 64-wide KV tile into buffer `buf` (4 loads/thread)
  auto stage = [&](int tile, int buf) {
    int kv0 = tile * 64;
#pragma unroll
    for (int j = 0; j < 2; ++j) {
      int idx = (wave * 2 + j) * 64 + lane;     // 0..1023
      {  // K: 64 rows x 16 atoms, swizzle ^(row&15)
        int r = idx >> 4, cs = idx & 15;
        int cc = cs ^ (r & 15);
        load_lds16(Kg + (size_t)(kv0 + r) * HD + cc * 8, &Kl[buf][idx * 8]);
      }
      {  // VT: 128 rows x 8 atoms, swizzle ^(row&7)
        int r = idx >> 3, cs = idx & 7;
        int cc = cs ^ (r & 7);
        load_lds16(Vg + (size_t)r * SEQ + kv0 + cc * 8, &Vl[buf][idx * 8]);
      }
    }
  };

  // prologue: tiles 0 and 1; vmcnt(4) retires Q-frags + stage(0),
  // leaves stage(1)'s 4 loads in flight.
  stage(0, 0);
  stage(1, 1);
  VMW4;
  BARR;

#pragma unroll 2
  for (int t = 0; t < 32; ++t) {
    const u16* Kb = Kl[t & 1];
    const u16* Vb = Vl[t & 1];

    // S^T tile: sc[nt], rows kv=nt*16+quad*4+r, cols q=l15
    f32x4 sc[4] = {};
    __builtin_amdgcn_s_setprio(1);
#pragma unroll
    for (int c = 0; c < 4; ++c) {
      bf16x8 kf[4];
#pragma unroll
      for (int nt = 0; nt < 4; ++nt)
        kf[nt] = *(const bf16x8*)&Kb[((nt * 16 + l15) * 16 +
                                      ((c * 4 + quad) ^ l15)) * 8];
#pragma unroll
      for (int nt = 0; nt < 4; ++nt)
        sc[nt] = __builtin_amdgcn_mfma_f32_16x16x32_bf16(
            kf[nt], qf[c], sc[nt], 0, 0, 0);
    }
    __builtin_amdgcn_s_setprio(0);

    // P = exp2(sc); truncate-pack via v_perm; b64 writes (wave-private Pl)
#pragma unroll
    for (int nt = 0; nt < 4; ++nt) {
      float p0 = __builtin_amdgcn_exp2f(sc[nt][0]);
      float p1 = __builtin_amdgcn_exp2f(sc[nt][1]);
      float p2 = __builtin_amdgcn_exp2f(sc[nt][2]);
      float p3 = __builtin_amdgcn_exp2f(sc[nt][3]);
      u32 lo = __builtin_amdgcn_perm(__float_as_uint(p1),
                                     __float_as_uint(p0), 0x07060302u);
      u32 hi = __builtin_amdgcn_perm(__float_as_uint(p3),
                                     __float_as_uint(p2), 0x07060302u);
      int a = nt * 2 + (quad >> 1);
      int idx16 = (l15 * 8 + (a ^ (l15 & 7))) * 8 + (quad & 1) * 4;
      uint2 pk; pk.x = lo; pk.y = hi;
      *(uint2_a*)&pw[idx16] = pk;
    }

    // O^T += V^T.P ; dt=8 uses the register ones-frag -> row sums (l)
    __builtin_amdgcn_s_setprio(1);
#pragma unroll
    for (int c = 0; c < 2; ++c) {
      bf16x8 pf = *(const bf16x8_a*)&pw[(l15 * 8 +
                                         ((c * 4 + quad) ^ (l15 & 7))) * 8];
#pragma unroll
      for (int dt = 0; dt < 9; ++dt) {
        bf16x8 vf = (dt < 8)
                        ? *(const bf16x8*)&Vb[((dt * 16 + l15) * 8 +
                                               ((c * 4 + quad) ^ (l15 & 7))) * 8]
                        : onesf;
        of[dt] = __builtin_amdgcn_mfma_f32_16x16x32_bf16(
            vf, pf, of[dt], 0, 0, 0);
      }
    }
    __builtin_amdgcn_s_setprio(0);

    // all waves done reading buf[t&1]; restage it for tile t+2
    BARR;
    if (t < 30) {
      stage(t + 2, t & 1);
      VMW4;              // stage(t+1) retired; stage(t+2) stays in flight
    } else {
      VMW0;              // tail: drain (covers stage(31) at t=30)
    }
    BARR;
  }

  // l lives at of[8][0] on quad-0 lanes (C row 0); broadcast by shfl.
  const int b = bh >> 4, h = bh & 15;
  {
    float lsum = __shfl(of[8][0], l15, 64);
    float inv = 1.f / lsum;
    int s = q0 + wave * 16 + l15;
    size_t rowb = ((size_t)b * SEQ + s) * DMODEL + h * HD;
#pragma unroll
    for (int dt = 0; dt < 8; ++dt) {
      ushort4 ov;
      ov.x = f2bf(of[dt][0] * inv);
      ov.y = f2bf(of[dt][1] * inv);
      ov.z = f2bf(of[dt][2] * inv);
      ov.w = f2bf(of[dt][3] * inv);
      *(ushort4*)&attn_out[rowb + dt * 16 + quad * 4] = ov;
    }
  }
}

extern "C" void kernel_launch(void* const* d_in, const int* in_sizes, int n_in,
                              void* d_out, int out_size, void* d_ws,
                              size_t ws_size, hipStream_t stream) {
  const float* x = (const float*)d_in[0];
  const float* Wq = (const float*)d_in[1];
  const float* Wk = (const float*)d_in[2];
  const float* Wv = (const float*)d_in[3];
  const float* Wo = (const float*)d_in[4];
  const float* bo = (const float*)d_in[5];
  float* out = (float*)d_out;

  char* ws = (char*)d_ws;
  u16* xb = (u16*)(ws);                              // 16 MiB
  u16* wqkv = (u16*)(ws + (size_t)(16 << 20));       // 24 MiB
  u16* wob = (u16*)(ws + (size_t)(40 << 20));        // 8 MiB
  u16* qkv = (u16*)(ws + (size_t)(48 << 20));        // 48 MiB: Q | K | vt
  u16* vt = qkv + (size_t)2 * 8388608;               // vt in the V slot
  u16* attn = xb;                                    // reuse after GEMMs

  // fp32 -> bf16 (one fused launch)
  conv_all<<<24576, 256, 0, stream>>>(x, Wq, Wk, Wv, Wo, xb, wqkv, wob);

  // Q,K (fused RoPE) + V^T: 256x128 tiles, 768 blocks = 3 exact CU-rounds
  gemm_qkv<<<dim3(48, 16), 512, 0, stream>>>(xb, wqkv, qkv, vt);
  // flash attention: 8 waves x 16 q-rows, 2 blocks/CU
  attn_kernel<<<dim3(16, 32), 512, 0, stream>>>(qkv, vt, attn);
  // out = attn @ wob^T + bo: 256x128 tiles, 256 blocks = 1 exact CU-round
  gemm_out<<<dim3(16, 16), 512, 0, stream>>>(attn, wob, out, bo);
}

// Round 7
// 343.117 us; speedup vs baseline: 1.0982x; 1.0703x over previous
//
#include <hip/hip_runtime.h>
#include <stdint.h>

// MultiHeadAttention: B=2, S=2048, D=2048, H=16, Dh=128, fp32 in/out.
// R12: best-of-both recombination. mm_core = R10 (triple-buffer, single
//      barrier/K-tile, counted vmcnt(6) -- verified 116->108us, MfmaUtil 41).
//      attn = R7/R9 4-wave form (32 q-rows/wave: 2 MFMAs per fragment read;
//      R11's 8-wave halved that ratio and went LDS-read-bound, +18us).
//      conv_all / gemm_out = R9 measured forms. No other changes.

#define SEQ 2048
#define HD 128
#define DMODEL 2048

typedef __bf16 bf16x8 __attribute__((ext_vector_type(8)));
typedef float f32x4 __attribute__((ext_vector_type(4)));
typedef unsigned short u16;
typedef unsigned int u32;

typedef bf16x8 __attribute__((may_alias)) bf16x8_a;
typedef uint2 __attribute__((may_alias)) uint2_a;
typedef uint4 __attribute__((may_alias)) uint4_a;

__device__ __forceinline__ u16 f2bf(float f) {
  unsigned int u = __float_as_uint(f);
  u += 0x7fff + ((u >> 16) & 1);   // RNE; inputs are finite normals
  return (u16)(u >> 16);
}

typedef __attribute__((address_space(1))) void* gas_t;
typedef __attribute__((address_space(3))) void* las_t;
// async global->LDS, 16B/lane. LDS dest must be uniform base + lane*16.
__device__ __forceinline__ void load_lds16(const void* g, void* l) {
  __builtin_amdgcn_global_load_lds((gas_t)(uintptr_t)g,
                                   (las_t)(uint32_t)(uintptr_t)l, 16, 0, 0);
}

// ---------------- fp32 -> bf16 convert (all 5 tensors, one launch) ---------
__global__ void conv_all(const float* __restrict__ x,
                         const float* __restrict__ wq,
                         const float* __restrict__ wk,
                         const float* __restrict__ wv,
                         const float* __restrict__ wo,
                         u16* __restrict__ xb, u16* __restrict__ wqkv,
                         u16* __restrict__ wob) {
  int i = blockIdx.x * 256 + threadIdx.x;  // float4 index
  const float* src;
  u16* dst;
  int off;
  if (i < 2097152) { src = x; dst = xb; off = i; }
  else if (i < 3145728) { src = wq; dst = wqkv; off = i - 2097152; }
  else if (i < 4194304) { src = wk; dst = wqkv + 4194304; off = i - 3145728; }
  else if (i < 5242880) { src = wv; dst = wqkv + 8388608; off = i - 4194304; }
  else { src = wo; dst = wob; off = i - 5242880; }
  float4 v = ((const float4*)src)[off];
  ushort4 o;
  o.x = f2bf(v.x); o.y = f2bf(v.y); o.z = f2bf(v.z); o.w = f2bf(v.w);
  ((ushort4*)dst)[off] = o;
}

// ============== 256x128-tile TRIPLE-buffered GEMM core (R10) ===============
// 8 waves 4M x 2N (wave tile 64x64, acc[4][4]); BK=64, K=2048 (32 K-tiles).
// LDS 144 KiB: A[3][256x64] (96 KB) + B[3][128x64] (48 KB).
// Per tile t (CUR = t%3 compile-time via 3-step unroll), ONE barrier:
//   { ds_read A01+B; STGA(t+2); MFMA(half0); ds_read A23; STGB(t+2);
//     MFMA(half1); vmcnt(6); s_barrier; }
// Ledger: at the barrier every wave's MFMAs are issued => their ds_reads of
// buf t%3 retired => buf t%3 dead, restaged at t+1 (as (t+3)%3). vmcnt(6)
// retires stage(t+1) (issued at t-1, ~2 tiles latency cover).

#define BARR asm volatile("s_barrier" ::: "memory")
#define VMW6 asm volatile("s_waitcnt vmcnt(6)" ::: "memory")
#define VMW8 asm volatile("s_waitcnt vmcnt(8)" ::: "memory")
#define VMW0 asm volatile("s_waitcnt vmcnt(0)" ::: "memory")

#define STGA(D, KOFF) do {                                                  \
    const u16* ga_ = Ag + (KOFF);                                           \
    u16* la_ = S + (D) * 16384;                                             \
    load_lds16(ga_ + off[0], la_ + tid * 8);                                \
    load_lds16(ga_ + off[1], la_ + (tid + 512) * 8);                        \
    load_lds16(ga_ + off[2], la_ + (tid + 1024) * 8);                       \
    load_lds16(ga_ + off[3], la_ + (tid + 1536) * 8);                       \
  } while (0)

#define STGB(D, KOFF) do {                                                  \
    const u16* gb_ = Bg + (KOFF);                                           \
    u16* lb_ = S + 49152 + (D) * 8192;                                      \
    load_lds16(gb_ + off[0], lb_ + tid * 8);                                \
    load_lds16(gb_ + off[1], lb_ + (tid + 512) * 8);                        \
  } while (0)

#define LDA2(D, MH) do {                                                    \
    const u16* ab_ = S + (D) * 16384;                                       \
    _Pragma("unroll") for (int mt_ = 0; mt_ < 2; ++mt_) {                   \
      int rA_ = wm * 64 + ((MH) * 2 + mt_) * 16 + l15;                      \
      int sw_ = rA_ & 7;                                                    \
      af[mt_][0] = *(const bf16x8_a*)(ab_ + (rA_ * 8 + (quad ^ sw_)) * 8);  \
      af[mt_][1] = *(const bf16x8_a*)(ab_ + (rA_ * 8 + ((4 + quad) ^ sw_)) * 8); \
    } } while (0)

#define LDB2(D) do {                                                        \
    const u16* bb_ = S + 49152 + (D) * 8192;                                \
    _Pragma("unroll") for (int nt_ = 0; nt_ < 4; ++nt_) {                   \
      int rB_ = wn * 64 + nt_ * 16 + l15;                                   \
      int sw_ = rB_ & 7;                                                    \
      bfr[nt_][0] = *(const bf16x8_a*)(bb_ + (rB_ * 8 + (quad ^ sw_)) * 8); \
      bfr[nt_][1] = *(const bf16x8_a*)(bb_ + (rB_ * 8 + ((4 + quad) ^ sw_)) * 8); \
    } } while (0)

#define MM2(MH) do {                                                        \
    __builtin_amdgcn_s_setprio(1);                                          \
    _Pragma("unroll") for (int c_ = 0; c_ < 2; ++c_)                        \
      _Pragma("unroll") for (int mt_ = 0; mt_ < 2; ++mt_)                   \
        _Pragma("unroll") for (int nt_ = 0; nt_ < 4; ++nt_) {               \
          if (VM)                                                           \
            acc[(MH) * 2 + mt_][nt_] =                                      \
                __builtin_amdgcn_mfma_f32_16x16x32_bf16(                    \
                    bfr[nt_][c_], af[mt_][c_],                              \
                    acc[(MH) * 2 + mt_][nt_], 0, 0, 0);                     \
          else                                                              \
            acc[(MH) * 2 + mt_][nt_] =                                      \
                __builtin_amdgcn_mfma_f32_16x16x32_bf16(                    \
                    af[mt_][c_], bfr[nt_][c_],                              \
                    acc[(MH) * 2 + mt_][nt_], 0, 0, 0);                     \
        }                                                                   \
    __builtin_amdgcn_s_setprio(0);                                          \
  } while (0)

// one steady-state K-tile, single barrier; CUR/NX2 compile-time
#define STEP3(T, CUR, NX2) do {                                             \
    LDA2(CUR, 0); LDB2(CUR);                                                \
    STGA(NX2, ((T) + 2) * 64);                                              \
    MM2(0);                                                                 \
    LDA2(CUR, 1);                                                           \
    STGB(NX2, ((T) + 2) * 64);                                              \
    MM2(1);                                                                 \
    VMW6; BARR;                                                             \
  } while (0)

template <bool VM>
__device__ __forceinline__ void mm_core(const u16* __restrict__ Ag,
                                        const u16* __restrict__ Bg,
                                        u16* __restrict__ S, int tid,
                                        f32x4 acc[4][4]) {
  const int lane = tid & 63;
  const int wave = tid >> 6;
  const int quad = lane >> 4;
  const int l15 = lane & 15;
  const int wm = wave >> 1;
  const int wn = wave & 1;

  // staging offsets: atom idx = tid + j*512; row = idx>>3 (stride K=2048);
  // source k8 pre-swizzled by ^(row&7); LDS dest linear (both-sides rule).
  u32 off[4];
#pragma unroll
  for (int j = 0; j < 4; ++j) {
    int idx = tid + j * 512;
    int r = idx >> 3;
    off[j] = (u32)r * 2048u + (u32)(((idx & 7) ^ (r & 7)) * 8);
  }

  bf16x8 af[2][2], bfr[4][2];

  // prologue: tiles 0 and 1 (A+B each); retire tile0, leave tile1 in flight
  STGA(0, 0);
  STGB(0, 0);
  STGA(1, 64);
  STGB(1, 64);
  VMW6;             // tile0's 6 loads retired; tile1's 6 in flight
  BARR;

  // t = 0..29 in groups of 3 (tt = 0,3,...,27 so tt % 3 == 0 always)
#pragma unroll 1
  for (int tt = 0; tt < 30; tt += 3) {
    STEP3(tt,     0, 2);
    STEP3(tt + 1, 1, 0);
    STEP3(tt + 2, 2, 1);
  }

  // t = 30 (CUR=0): no staging; drain stage(31) for t=31
  LDA2(0, 0); LDB2(0);
  MM2(0);
  LDA2(0, 1);
  MM2(1);
  VMW0; BARR;
  // t = 31 (CUR=1)
  LDA2(1, 0); LDB2(1);
  MM2(0);
  LDA2(1, 1);
  MM2(1);
  BARR;             // all reads done before epilogue reuses S
}

// grid (48, 16), 512 threads. bx<16: Q RoPE; 16-31: K RoPE; 32-47: V^T.
__global__ __launch_bounds__(512, 2)
void gemm_qkv(const u16* __restrict__ A, const u16* __restrict__ Bm,
              u16* __restrict__ qkv, u16* __restrict__ vt) {
  __shared__ __align__(16) u16 S[73728];  // 144 KiB: A[3][16384]+B[3][8192]

  const int tid = threadIdx.x;
  // XCD-aware bijective swizzle, col-major logical order: each XCD owns 6
  // consecutive B-panels (weights resident in its L2); A panels hit L3.
  int hwid = blockIdx.y * 48 + blockIdx.x;
  int logical = (hwid & 7) * 96 + (hwid >> 3);
  const int bx = logical >> 4;       // 0..47 (N tile, 128 cols = 1 head)
  const int by = logical & 15;       // 0..15 (M tile, 256 rows)
  const int row0 = by * 256;
  const int col0 = bx * 128;
  const bool vmode = bx >= 32;

  const u16* Ag = A + (size_t)row0 * 2048;
  const u16* Bg = Bm + (size_t)col0 * 2048;

  f32x4 acc[4][4] = {};
  if (vmode) mm_core<true>(Ag, Bg, S, tid, acc);
  else       mm_core<false>(Ag, Bg, S, tid, acc);

  const int lane = tid & 63;
  const int wave = tid >> 6;
  const int quad = lane >> 4;
  const int l15 = lane & 15;
  const int wm = wave >> 1;
  const int wn = wave & 1;

  const int which = bx >> 4;              // 0=q 1=k 2=v
  const int h = bx & 15;
  const int brow = row0 >> 11;
  const int sbase = row0 & 2047;
  const float qs = (which == 0) ? 0.12751744f : 1.0f;  // log2e/sqrt(128)

  // acc -> bf16 tile in S (reuses A region), atom-XOR swizzled
#pragma unroll
  for (int mt = 0; mt < 4; ++mt)
#pragma unroll
    for (int nt = 0; nt < 4; ++nt)
#pragma unroll
      for (int r = 0; r < 4; ++r) {
        int el;
        if (vmode) {  // C^T tile [d=128][s=256], 32 atoms/row
          int dd = wn * 64 + nt * 16 + quad * 4 + r;
          int ss = wm * 64 + mt * 16 + l15;
          el = dd * 256 + (((ss >> 3) ^ (dd & 31)) * 8) + (ss & 7);
        } else {      // tile [s=256][d=128], 16 atoms/row
          int ss = wm * 64 + mt * 16 + quad * 4 + r;
          int dd = wn * 64 + nt * 16 + l15;
          el = ss * 128 + (((dd >> 3) ^ (ss & 15)) * 8) + (dd & 7);
        }
        S[el] = f2bf(acc[mt][nt][r] * qs);
      }
  __syncthreads();

  if (!vmode) {
    const int a = lane & 7;     // d-atom 0..7 (pairs with a+8)
    const int sg = lane >> 3;   // row-in-group
    const float c1 = 0.2076205059304601f;   // log2(10000)/64
    const float c2 = 2.6514961294723187f;   // log2(2*pi)
#pragma unroll
    for (int pass = 0; pass < 4; ++pass) {
      int s_l = pass * 64 + wave * 8 + sg;
      int s2048 = sbase + s_l;
      int sw = s_l & 15;
      bf16x8 x1 = *(const bf16x8_a*)&S[s_l * 128 + ((a ^ sw) * 8)];
      bf16x8 x2 = *(const bf16x8_a*)&S[s_l * 128 + (((a + 8) ^ sw) * 8)];
      u16 o1[8], o2[8];
#pragma unroll
      for (int e = 0; e < 8; ++e) {
        float j = (float)(a * 8 + e);
        float rev = (float)s2048 * __builtin_amdgcn_exp2f(-c1 * j - c2);
        rev = __builtin_amdgcn_fractf(rev);
        float sn = __builtin_amdgcn_sinf(rev);
        float cs = __builtin_amdgcn_cosf(rev);
        float v1 = (float)x1[e], v2 = (float)x2[e];
        o1[e] = f2bf(v1 * cs - v2 * sn);
        o2[e] = f2bf(v2 * cs + v1 * sn);
      }
      size_t base =
          ((((size_t)which * 2 + brow) * 16 + h) * SEQ + s2048) * HD + a * 8;
      *(uint4_a*)&qkv[base] = *(uint4*)o1;
      *(uint4_a*)&qkv[base + 64] = *(uint4*)o2;
    }
  } else {  // V: transposed copy-out, vt[b,h,d,s]
    const int d_part = tid >> 4;        // 0..31
    const int a0 = tid & 15;            // atom 0..15 (+16 for second)
#pragma unroll
    for (int pass = 0; pass < 4; ++pass) {
      int d_l = pass * 32 + d_part;     // 0..127
      int dw = d_l & 31;
      size_t rb = (((size_t)brow * 16 + h) * HD + d_l) * SEQ + sbase;
#pragma unroll
      for (int g = 0; g < 2; ++g) {
        int a2 = a0 + g * 16;
        bf16x8 y = *(const bf16x8_a*)&S[d_l * 256 + ((a2 ^ dw) * 8)];
        *(uint4_a*)&vt[rb + a2 * 8] = *(uint4_a*)&y;
      }
    }
  }
}

// ---------------- output GEMM: same core, fp32 + bias epilogue (R9) --------
// grid (16, 16) = 256 blocks = exactly 1 CU-round.
__global__ __launch_bounds__(512, 2)
void gemm_out(const u16* __restrict__ A, const u16* __restrict__ Bm,
              float* __restrict__ C, const float* __restrict__ bias) {
  __shared__ __align__(16) u16 S[73728];  // 144 KiB

  const int tid = threadIdx.x;
  int hwid = blockIdx.y * 16 + blockIdx.x;
  int logical = (hwid & 7) * 32 + (hwid >> 3);
  const int bx = logical >> 4;       // 0..15 (N tile)
  const int by = logical & 15;       // 0..15 (M tile)
  const int row0 = by * 256;
  const int col0 = bx * 128;

  const u16* Ag = A + (size_t)row0 * 2048;
  const u16* Bg = Bm + (size_t)col0 * 2048;

  f32x4 acc[4][4] = {};
  mm_core<false>(Ag, Bg, S, tid, acc);

  const int lane = tid & 63;
  const int wave = tid >> 6;
  const int quad = lane >> 4;
  const int l15 = lane & 15;
  const int wm = wave >> 1;
  const int wn = wave & 1;

#pragma unroll
  for (int nt = 0; nt < 4; ++nt) {
    int d = col0 + wn * 64 + nt * 16 + l15;
    float bv = bias[d];
#pragma unroll
    for (int mt = 0; mt < 4; ++mt) {
#pragma unroll
      for (int r = 0; r < 4; ++r) {
        int row = row0 + wm * 64 + mt * 16 + quad * 4 + r;
        C[(size_t)row * DMODEL + d] = acc[mt][nt][r] + bv;
      }
    }
  }
}

// ---------------- Flash attention (R7 form: 4 waves x 32 q-rows) -----------
// grid (S/128, B*H), 256 threads; wave owns 32 Q rows (2 m-tiles).
// KV double-buffer; per tile t: compute on buf[t&1]; BARR; stage(t+2)->
// buf[t&1]; vmcnt(8) (stage(t+1) retired, stage(t+2) in flight); BARR.
// setprio(1) around both MFMA clusters. 2 blocks/CU (80 KiB LDS).
__global__ __launch_bounds__(256, 2)
void attn_kernel(const u16* __restrict__ qkv, const u16* __restrict__ vt,
                 u16* __restrict__ attn_out) {
  __shared__ __align__(16) u16 Kl[2][64 * 128];   // [kv][hd] swizzled atoms
  __shared__ __align__(16) u16 Vl[2][128 * 64];   // [d][kv] swizzled atoms
  __shared__ __align__(16) u16 Pl[4][32 * 64];    // per-wave [q][kv] swizzled

  const int tid = threadIdx.x;
  const int lane = tid & 63;
  const int wave = tid >> 6;
  const int quad = lane >> 4;
  const int l15 = lane & 15;
  const int q0 = blockIdx.x * 128;
  const int bh = blockIdx.y;
  const size_t SD = (size_t)SEQ * HD;

  const u16* Q = qkv + (size_t)bh * SD;          // which=0 (pre-scaled)
  const u16* Kg = qkv + (size_t)(32 + bh) * SD;  // which=1
  const u16* Vg = vt + (size_t)bh * SD;          // [d][s]

  // ones A-fragment in registers: row m=0 (lanes l15==0) = 1.0, else 0.
  bf16x8 onesf;
#pragma unroll
  for (int e = 0; e < 8; ++e)
    onesf[e] = (l15 == 0) ? (__bf16)1.0f : (__bf16)0.0f;

  // Q fragments first: oldest in the vmcnt FIFO, retired before first use.
  bf16x8 qf[2][4];  // Q[q=mt*16+l15][hd=c*32+quad*8+j]
#pragma unroll
  for (int mt = 0; mt < 2; ++mt) {
    int qrow = q0 + wave * 32 + mt * 16 + l15;
#pragma unroll
    for (int c = 0; c < 4; ++c)
      qf[mt][c] = *(const bf16x8*)(Q + (size_t)qrow * HD + c * 32 + quad * 8);
  }

  f32x4 of[9][2] = {};   // of[0..7]: O^T[d][q]; of[8] row0: l (ones frag)
  u16* pw = &Pl[wave][0];

  // stage one 64-wide KV tile into buffer `buf` (8 loads/thread)
  auto stage = [&](int tile, int buf) {
    int kv0 = tile * 64;
#pragma unroll
    for (int j = 0; j < 4; ++j) {
      int idx = (wave * 4 + j) * 64 + lane;
      {  // K: 64 rows x 16 atoms, swizzle ^(row&15)
        int r = idx >> 4, cs = idx & 15;
        int cc = cs ^ (r & 15);
        load_lds16(Kg + (size_t)(kv0 + r) * HD + cc * 8, &Kl[buf][idx * 8]);
      }
      {  // VT: 128 rows x 8 atoms, swizzle ^(row&7)
        int r = idx >> 3, cs = idx & 7;
        int cc = cs ^ (r & 7);
        load_lds16(Vg + (size_t)r * SEQ + kv0 + cc * 8, &Vl[buf][idx * 8]);
      }
    }
  };

  // prologue: tiles 0 and 1; vmcnt(8) = stage(0) retired (stage(1) in flight)
  stage(0, 0);
  stage(1, 1);
  VMW8;
  BARR;

#pragma unroll 2
  for (int t = 0; t < 32; ++t) {
    const u16* Kb = Kl[t & 1];
    const u16* Vb = Vl[t & 1];

    // S^T tiles: sc[nt][mt], rows kv=nt*16+quad*4+r, cols q=mt*16+l15
    f32x4 sc[4][2] = {};
    __builtin_amdgcn_s_setprio(1);
#pragma unroll
    for (int c = 0; c < 4; ++c) {
      bf16x8 kf[4];
#pragma unroll
      for (int nt = 0; nt < 4; ++nt)
        kf[nt] = *(const bf16x8*)&Kb[((nt * 16 + l15) * 16 +
                                      ((c * 4 + quad) ^ l15)) * 8];
#pragma unroll
      for (int nt = 0; nt < 4; ++nt)
#pragma unroll
        for (int mt = 0; mt < 2; ++mt)
          sc[nt][mt] = __builtin_amdgcn_mfma_f32_16x16x32_bf16(
              kf[nt], qf[mt][c], sc[nt][mt], 0, 0, 0);
    }
    __builtin_amdgcn_s_setprio(0);

    // P = exp2(sc); truncate-pack via v_perm; b64 writes (wave-private Pl)
#pragma unroll
    for (int nt = 0; nt < 4; ++nt) {
#pragma unroll
      for (int mt = 0; mt < 2; ++mt) {
        float p0 = __builtin_amdgcn_exp2f(sc[nt][mt][0]);
        float p1 = __builtin_amdgcn_exp2f(sc[nt][mt][1]);
        float p2 = __builtin_amdgcn_exp2f(sc[nt][mt][2]);
        float p3 = __builtin_amdgcn_exp2f(sc[nt][mt][3]);
        u32 lo = __builtin_amdgcn_perm(__float_as_uint(p1),
                                       __float_as_uint(p0), 0x07060302u);
        u32 hi = __builtin_amdgcn_perm(__float_as_uint(p3),
                                       __float_as_uint(p2), 0x07060302u);
        int row = mt * 16 + l15;
        int a = nt * 2 + (quad >> 1);
        int idx16 = (row * 8 + (a ^ (l15 & 7))) * 8 + (quad & 1) * 4;
        uint2 pk; pk.x = lo; pk.y = hi;
        *(uint2_a*)&pw[idx16] = pk;
      }
    }

    // O^T += V^T.P ; dt=8 uses the register ones-frag -> row sums (l)
    __builtin_amdgcn_s_setprio(1);
#pragma unroll
    for (int c = 0; c < 2; ++c) {
      bf16x8 pf[2];
#pragma unroll
      for (int mt = 0; mt < 2; ++mt)
        pf[mt] = *(const bf16x8_a*)&pw[((mt * 16 + l15) * 8 +
                                        ((c * 4 + quad) ^ (l15 & 7))) * 8];
#pragma unroll
      for (int dt = 0; dt < 9; ++dt) {
        bf16x8 vf = (dt < 8)
                        ? *(const bf16x8*)&Vb[((dt * 16 + l15) * 8 +
                                               ((c * 4 + quad) ^ (l15 & 7))) * 8]
                        : onesf;
#pragma unroll
        for (int mt = 0; mt < 2; ++mt)
          of[dt][mt] = __builtin_amdgcn_mfma_f32_16x16x32_bf16(
              vf, pf[mt], of[dt][mt], 0, 0, 0);
      }
    }
    __builtin_amdgcn_s_setprio(0);

    // all waves done reading buf[t&1]; restage it for tile t+2
    BARR;
    if (t < 30) {
      stage(t + 2, t & 1);
      VMW8;              // stage(t+1) retired; stage(t+2) stays in flight
    } else {
      VMW0;              // tail: drain (covers stage(31) at t=30)
    }
    BARR;
  }

  // l lives at of[8][mt][0] on quad-0 lanes (C row 0); broadcast by shfl.
  const int b = bh >> 4, h = bh & 15;
#pragma unroll
  for (int mt = 0; mt < 2; ++mt) {
    float lsum = __shfl(of[8][mt][0], l15, 64);
    float inv = 1.f / lsum;
    int s = q0 + wave * 32 + mt * 16 + l15;
    size_t rowb = ((size_t)b * SEQ + s) * DMODEL + h * HD;
#pragma unroll
    for (int dt = 0; dt < 8; ++dt) {
      ushort4 ov;
      ov.x = f2bf(of[dt][mt][0] * inv);
      ov.y = f2bf(of[dt][mt][1] * inv);
      ov.z = f2bf(of[dt][mt][2] * inv);
      ov.w = f2bf(of[dt][mt][3] * inv);
      *(ushort4*)&attn_out[rowb + dt * 16 + quad * 4] = ov;
    }
  }
}

extern "C" void kernel_launch(void* const* d_in, const int* in_sizes, int n_in,
                              void* d_out, int out_size, void* d_ws,
                              size_t ws_size, hipStream_t stream) {
  const float* x = (const float*)d_in[0];
  const float* Wq = (const float*)d_in[1];
  const float* Wk = (const float*)d_in[2];
  const float* Wv = (const float*)d_in[3];
  const float* Wo = (const float*)d_in[4];
  const float* bo = (const float*)d_in[5];
  float* out = (float*)d_out;

  char* ws = (char*)d_ws;
  u16* xb = (u16*)(ws);                              // 16 MiB
  u16* wqkv = (u16*)(ws + (size_t)(16 << 20));       // 24 MiB
  u16* wob = (u16*)(ws + (size_t)(40 << 20));        // 8 MiB
  u16* qkv = (u16*)(ws + (size_t)(48 << 20));        // 48 MiB: Q | K | vt
  u16* vt = qkv + (size_t)2 * 8388608;               // vt in the V slot
  u16* attn = xb;                                    // reuse after GEMMs

  // fp32 -> bf16 (one fused launch)
  conv_all<<<24576, 256, 0, stream>>>(x, Wq, Wk, Wv, Wo, xb, wqkv, wob);

  // Q,K (fused RoPE) + V^T: 256x128 tiles, 768 blocks = 3 exact CU-rounds
  gemm_qkv<<<dim3(48, 16), 512, 0, stream>>>(xb, wqkv, qkv, vt);
  // flash attention: 4 waves x 32 q-rows, 2 blocks/CU
  attn_kernel<<<dim3(16, 32), 256, 0, stream>>>(qkv, vt, attn);
  // out = attn @ wob^T + bo: 256x128 tiles, 256 blocks = 1 exact CU-round
  gemm_out<<<dim3(16, 16), 512, 0, stream>>>(attn, wob, out, bo);
}